// Round 3
// baseline (1305.772 us; speedup 1.0000x reference)
//
#include <hip/hip_runtime.h>

// Outputs (concatenated flat in d_out, all float32):
//   loss     [B*16]      = (x - y)^2
//   d_loss   [B*16]      = 2*(x - y)
//   sqd_loss [B*16*16]   = per-sample Hessian = 2*I_16 (input-independent)
//
// Single fused grid-stride kernel, 2048 blocks x 256 threads. Grid stride in
// floats = 2,097,152 (multiple of 256), so each thread's offset within the
// repeating 256-float (16x16) Hessian pattern is loop-invariant: compute the
// 2*I float4 once, then the hess loop is pure nontemporal dwordx4 stores.
//
// NOTE: __builtin_nontemporal_store requires a clang vector type, not HIP's
// float4 class — use ext_vector_type(4).

typedef float vfloat4 __attribute__((ext_vector_type(4)));

__global__ __launch_bounds__(256) void fused_autograd_kernel(
    const vfloat4* __restrict__ x,
    const vfloat4* __restrict__ y,
    vfloat4* __restrict__ loss,
    vfloat4* __restrict__ dloss,
    vfloat4* __restrict__ sqd,
    unsigned int loss_n4,
    unsigned int hess_n4) {
    const unsigned int tid    = blockIdx.x * blockDim.x + threadIdx.x;
    const unsigned int stride = gridDim.x * blockDim.x;  // 524,288 float4s

    // ---- loss + d_loss: read 2 streams, write 2 streams ----
    for (unsigned int i = tid; i < loss_n4; i += stride) {
        vfloat4 a = x[i];
        vfloat4 b = y[i];
        vfloat4 d = a - b;
        vfloat4 l = d * d;
        vfloat4 g = d + d;
        __builtin_nontemporal_store(l, &loss[i]);
        __builtin_nontemporal_store(g, &dloss[i]);
    }

    // ---- Hessian fill: 2*I_16 per 256-float block, pattern loop-invariant ----
    const unsigned int f   = (tid << 2) & 255u;  // float offset within 16x16 block
    const unsigned int col = f & 15u;            // 0,4,8,12
    const unsigned int row = (f >> 4) & 15u;
    vfloat4 v;
    v.x = (row == col)      ? 2.0f : 0.0f;
    v.y = (row == col + 1u) ? 2.0f : 0.0f;
    v.z = (row == col + 2u) ? 2.0f : 0.0f;
    v.w = (row == col + 3u) ? 2.0f : 0.0f;

    for (unsigned int i = tid; i < hess_n4; i += stride) {
        __builtin_nontemporal_store(v, &sqd[i]);
    }
}

extern "C" void kernel_launch(void* const* d_in, const int* in_sizes, int n_in,
                              void* d_out, int out_size, void* d_ws, size_t ws_size,
                              hipStream_t stream) {
    const float* model_out = (const float*)d_in[0];
    const float* y_true    = (const float*)d_in[1];
    float* out = (float*)d_out;

    const int BD = in_sizes[0];              // B*16 = 16,777,216
    float* loss_p  = out;                    // [BD]
    float* dloss_p = out + BD;               // [BD]
    float* sqd_p   = out + 2 * (size_t)BD;   // [BD*16]

    const unsigned int loss_n4 = (unsigned int)(BD / 4);               // 4,194,304
    const unsigned int hess_n4 = (unsigned int)((size_t)BD * 16 / 4);  // 67,108,864

    const int block = 256;
    const int grid  = 2048;  // 8 blocks/CU on 256 CUs; grid-stride covers all

    fused_autograd_kernel<<<grid, block, 0, stream>>>(
        (const vfloat4*)model_out, (const vfloat4*)y_true,
        (vfloat4*)loss_p, (vfloat4*)dloss_p, (vfloat4*)sqd_p,
        loss_n4, hess_n4);
}

// Round 4
// 1275.044 us; speedup vs baseline: 1.0241x; 1.0241x over previous
//
#include <hip/hip_runtime.h>

// Outputs (concatenated flat in d_out, all float32):
//   loss     [B*16]      = (x - y)^2
//   d_loss   [B*16]      = 2*(x - y)
//   sqd_loss [B*16*16]   = per-sample Hessian = 2*I_16 (input-independent)
//
// Persistent grid-stride kernel: 2048 blocks x 256 threads = 8192 waves =
// exactly 32 waves/CU on 256 CUs. PLAIN stores (R3 showed nontemporal `nt`
// stores regress write BW ~15% vs the rocclr fill's plain stores).
// Hess pattern value is loop-invariant per thread (stride multiple of 256
// floats); loop manually unrolled x4 -> 4 independent dwordx4 stores in
// flight per thread per iteration, mirroring the 6.26 TB/s fill structure.

typedef float vfloat4 __attribute__((ext_vector_type(4)));

__global__ __launch_bounds__(256) void fused_autograd_kernel(
    const vfloat4* __restrict__ x,
    const vfloat4* __restrict__ y,
    vfloat4* __restrict__ loss,
    vfloat4* __restrict__ dloss,
    vfloat4* __restrict__ sqd,
    unsigned int loss_n4,
    unsigned int hess_n4) {
    const unsigned int tid    = blockIdx.x * blockDim.x + threadIdx.x;
    const unsigned int stride = gridDim.x * blockDim.x;  // 524,288 float4s

    // ---- loss + d_loss: 8 iterations, unrolled x2 ----
    for (unsigned int i = tid; i < loss_n4; i += 2u * stride) {
        unsigned int i1 = i + stride;
        vfloat4 a0 = x[i];
        vfloat4 b0 = y[i];
        vfloat4 a1 = x[i1];
        vfloat4 b1 = y[i1];
        vfloat4 d0 = a0 - b0;
        vfloat4 d1 = a1 - b1;
        loss[i]   = d0 * d0;
        dloss[i]  = d0 + d0;
        loss[i1]  = d1 * d1;
        dloss[i1] = d1 + d1;
    }

    // ---- Hessian fill: 2*I_16, pattern loop-invariant per thread ----
    const unsigned int f   = (tid << 2) & 255u;  // float offset within 16x16 block
    const unsigned int col = f & 15u;            // 0,4,8,12
    const unsigned int row = (f >> 4) & 15u;
    vfloat4 v;
    v.x = (row == col)      ? 2.0f : 0.0f;
    v.y = (row == col + 1u) ? 2.0f : 0.0f;
    v.z = (row == col + 2u) ? 2.0f : 0.0f;
    v.w = (row == col + 3u) ? 2.0f : 0.0f;

    // 128 stores/thread, unrolled x4 (hess_n4 = 128 * stride exactly)
    for (unsigned int i = tid; i < hess_n4; i += 4u * stride) {
        sqd[i]               = v;
        sqd[i + stride]      = v;
        sqd[i + 2u * stride] = v;
        sqd[i + 3u * stride] = v;
    }
}

extern "C" void kernel_launch(void* const* d_in, const int* in_sizes, int n_in,
                              void* d_out, int out_size, void* d_ws, size_t ws_size,
                              hipStream_t stream) {
    const float* model_out = (const float*)d_in[0];
    const float* y_true    = (const float*)d_in[1];
    float* out = (float*)d_out;

    const int BD = in_sizes[0];              // B*16 = 16,777,216
    float* loss_p  = out;                    // [BD]
    float* dloss_p = out + BD;               // [BD]
    float* sqd_p   = out + 2 * (size_t)BD;   // [BD*16]

    const unsigned int loss_n4 = (unsigned int)(BD / 4);               // 4,194,304
    const unsigned int hess_n4 = (unsigned int)((size_t)BD * 16 / 4);  // 67,108,864

    const int block = 256;
    const int grid  = 2048;  // 8192 waves = 32 waves/CU x 256 CUs

    fused_autograd_kernel<<<grid, block, 0, stream>>>(
        (const vfloat4*)model_out, (const vfloat4*)y_true,
        (vfloat4*)loss_p, (vfloat4*)dloss_p, (vfloat4*)sqd_p,
        loss_n4, hess_n4);
}